// Round 3
// baseline (540.684 us; speedup 1.0000x reference)
//
#include <hip/hip_runtime.h>

#define N_NODES    100000
#define N_EDGES    1200000
#define HIDDEN     64
#define NUM_ATOM   100
#define SCAN_BLOCK 256

// ---------------------------------------------------------------------------
// rank[e] = deg[row[e]]++   (int atomics, L2-resident histogram; rank seq write)
__global__ void deg_rank_kernel(const int* __restrict__ row,
                                int* __restrict__ deg, int* __restrict__ rank) {
    int e = blockIdx.x * blockDim.x + threadIdx.x;
    if (e >= N_EDGES) return;
    rank[e] = atomicAdd(&deg[row[e]], 1);
}

// Block-level exclusive scan (Hillis-Steele) + per-block sums
__global__ void scan1_kernel(const int* __restrict__ deg, int* __restrict__ offs,
                             int* __restrict__ bsums) {
    __shared__ int tmp[SCAN_BLOCK];
    int i = blockIdx.x * SCAN_BLOCK + threadIdx.x;
    int v = (i < N_NODES) ? deg[i] : 0;
    tmp[threadIdx.x] = v;
    __syncthreads();
    for (int off = 1; off < SCAN_BLOCK; off <<= 1) {
        int t = (threadIdx.x >= off) ? tmp[threadIdx.x - off] : 0;
        __syncthreads();
        tmp[threadIdx.x] += t;
        __syncthreads();
    }
    if (i < N_NODES) offs[i] = tmp[threadIdx.x] - v;   // exclusive
    if (threadIdx.x == SCAN_BLOCK - 1) bsums[blockIdx.x] = tmp[threadIdx.x];
}

// Single-block exclusive scan of the block sums
__global__ void scan2_kernel(int* __restrict__ bsums, int nb) {
    __shared__ int tmp[512];
    int v = (threadIdx.x < nb) ? bsums[threadIdx.x] : 0;
    tmp[threadIdx.x] = v;
    __syncthreads();
    for (int off = 1; off < 512; off <<= 1) {
        int t = (threadIdx.x >= off) ? tmp[threadIdx.x - off] : 0;
        __syncthreads();
        tmp[threadIdx.x] += t;
        __syncthreads();
    }
    if (threadIdx.x < nb) bsums[threadIdx.x] = tmp[threadIdx.x] - v;  // exclusive
}

__global__ void scan3_kernel(int* __restrict__ offs, const int* __restrict__ bsums) {
    int i = blockIdx.x * SCAN_BLOCK + threadIdx.x;
    if (i >= N_NODES) return;
    offs[i] += bsums[blockIdx.x];
}

// csr_col[offs[row[e]] + rank[e]] = col[e]   (no atomics)
__global__ void fill_kernel(const int* __restrict__ row, const int* __restrict__ col,
                            const int* __restrict__ offs, const int* __restrict__ rank,
                            int* __restrict__ csr_col) {
    int e = blockIdx.x * blockDim.x + threadIdx.x;
    if (e >= N_EDGES) return;
    csr_col[offs[row[e]] + rank[e]] = col[e];
}

// ---------------------------------------------------------------------------
// Layer 1 fused with embedding: emb (25.6 KB) lives in LDS; gather reads only
// z[c] (4 B, L2-resident) per edge instead of a 256 B x-row.
__global__ __launch_bounds__(256) void layer1_kernel(
        const int* __restrict__ z, const float* __restrict__ emb,
        float* __restrict__ xout,
        const int* __restrict__ offs, const int* __restrict__ csr_col,
        const float* __restrict__ W, const float* __restrict__ b) {
    __shared__ float Es[NUM_ATOM * 64];   // 25.6 KB
    __shared__ float Ws[64][65];          // +1 pad -> 2 lanes/bank (free)
    __shared__ float xs[4][64];

    int t = threadIdx.x;
    for (int i = t; i < NUM_ATOM * 64; i += 256) Es[i] = emb[i];
    for (int i = t; i < 4096; i += 256) Ws[i >> 6][i & 63] = W[i];
    __syncthreads();

    int lane = t & 63, w = t >> 6;
    float bb = b[lane];
    int tw = gridDim.x * 4;

    for (int n = blockIdx.x * 4 + w; n < N_NODES; n += tw) {
        int s = offs[n];
        int e = (n == N_NODES - 1) ? N_EDGES : offs[n + 1];

        float acc = Es[z[n] * 64 + lane];
        float a0=0.f,a1=0.f,a2=0.f,a3=0.f,a4=0.f,a5=0.f,a6=0.f,a7=0.f;
        int k = s;
        for (; k + 7 < e; k += 8) {
            int c0=csr_col[k],   c1=csr_col[k+1], c2=csr_col[k+2], c3=csr_col[k+3];
            int c4=csr_col[k+4], c5=csr_col[k+5], c6=csr_col[k+6], c7=csr_col[k+7];
            int z0=z[c0], z1=z[c1], z2=z[c2], z3=z[c3];
            int z4=z[c4], z5=z[c5], z6=z[c6], z7=z[c7];
            a0 += Es[z0*64+lane]; a1 += Es[z1*64+lane];
            a2 += Es[z2*64+lane]; a3 += Es[z3*64+lane];
            a4 += Es[z4*64+lane]; a5 += Es[z5*64+lane];
            a6 += Es[z6*64+lane]; a7 += Es[z7*64+lane];
        }
        for (; k < e; ++k) acc += Es[z[csr_col[k]] * 64 + lane];
        acc += ((a0+a1)+(a2+a3)) + ((a4+a5)+(a6+a7));

        xs[w][lane] = acc;   // wave-synchronous exchange

        float o = bb;
        #pragma unroll
        for (int kk = 0; kk < 64; ++kk)
            o = fmaf(xs[w][kk], Ws[lane][kk], o);
        xout[n * 64 + lane] = fmaxf(o, 0.0f);
    }
}

// ---------------------------------------------------------------------------
// Layers 2..3: aggregate (gather) + residual + linear + ReLU.
// W in LDS (not VGPRs) -> low VGPR -> 8 waves/SIMD; 8 independent gather chains.
__global__ __launch_bounds__(256, 8) void layer_kernel(
        const float* __restrict__ xin, float* __restrict__ xout,
        const int* __restrict__ offs, const int* __restrict__ csr_col,
        const float* __restrict__ W, const float* __restrict__ b) {
    __shared__ float Ws[64][65];
    __shared__ float xs[4][64];

    int t = threadIdx.x;
    for (int i = t; i < 4096; i += 256) Ws[i >> 6][i & 63] = W[i];
    __syncthreads();

    int lane = t & 63, w = t >> 6;
    float bb = b[lane];
    int tw = gridDim.x * 4;

    for (int n = blockIdx.x * 4 + w; n < N_NODES; n += tw) {
        int s = offs[n];
        int e = (n == N_NODES - 1) ? N_EDGES : offs[n + 1];

        float acc = xin[n * 64 + lane];
        float a0=0.f,a1=0.f,a2=0.f,a3=0.f,a4=0.f,a5=0.f,a6=0.f,a7=0.f;
        int k = s;
        for (; k + 7 < e; k += 8) {
            int c0=csr_col[k],   c1=csr_col[k+1], c2=csr_col[k+2], c3=csr_col[k+3];
            int c4=csr_col[k+4], c5=csr_col[k+5], c6=csr_col[k+6], c7=csr_col[k+7];
            a0 += xin[c0*64+lane]; a1 += xin[c1*64+lane];
            a2 += xin[c2*64+lane]; a3 += xin[c3*64+lane];
            a4 += xin[c4*64+lane]; a5 += xin[c5*64+lane];
            a6 += xin[c6*64+lane]; a7 += xin[c7*64+lane];
        }
        for (; k < e; ++k) acc += xin[csr_col[k] * 64 + lane];
        acc += ((a0+a1)+(a2+a3)) + ((a4+a5)+(a6+a7));

        xs[w][lane] = acc;   // wave-synchronous exchange

        float o = bb;
        #pragma unroll
        for (int kk = 0; kk < 64; ++kk)
            o = fmaf(xs[w][kk], Ws[lane][kk], o);
        xout[n * 64 + lane] = fmaxf(o, 0.0f);
    }
}

// ---------------------------------------------------------------------------
extern "C" void kernel_launch(void* const* d_in, const int* in_sizes, int n_in,
                              void* d_out, int out_size, void* d_ws, size_t ws_size,
                              hipStream_t stream) {
    const int*   z          = (const int*)d_in[0];
    const int*   edge_index = (const int*)d_in[1];
    const float* emb        = (const float*)d_in[2];
    const float* W          = (const float*)d_in[3];
    const float* b          = (const float*)d_in[4];

    const int* row = edge_index;             // edge_index[0]
    const int* col = edge_index + N_EDGES;   // edge_index[1]

    float* x_out = (float*)d_out;            // [N][64]

    // workspace layout (rank aliases x_a: rank is dead before layer 1 writes x_a)
    char* wsb = (char*)d_ws;
    float* x_a     = (float*)wsb;                         // 25,600,000 B
    int*   rank    = (int*)wsb;                           // first 4,800,000 B of x_a
    int*   csr_col = (int*)(wsb + 25600000);              //  4,800,000 B
    int*   deg     = (int*)(wsb + 30400000);              //    400,128 B
    int*   offs    = (int*)(wsb + 30800128);              //    400,128 B
    int*   bsums   = (int*)(wsb + 31200256);              //      2,048 B

    const int nb = (N_NODES + SCAN_BLOCK - 1) / SCAN_BLOCK;   // 391

    // ---- build CSR ----
    hipMemsetAsync(deg, 0, N_NODES * sizeof(int), stream);
    deg_rank_kernel<<<(N_EDGES + 255) / 256, 256, 0, stream>>>(row, deg, rank);
    scan1_kernel<<<nb, SCAN_BLOCK, 0, stream>>>(deg, offs, bsums);
    scan2_kernel<<<1, 512, 0, stream>>>(bsums, nb);
    scan3_kernel<<<nb, SCAN_BLOCK, 0, stream>>>(offs, bsums);
    fill_kernel<<<(N_EDGES + 255) / 256, 256, 0, stream>>>(row, col, offs, rank, csr_col);

    // ---- 3 fused layers: L1 (embed fused) -> d_out, L2 -> x_a, L3 -> d_out ----
    const int LBLOCKS = 2048;
    layer1_kernel<<<LBLOCKS, 256, 0, stream>>>(z, emb, x_out, offs, csr_col,
                                               W + 0 * HIDDEN * HIDDEN, b + 0 * HIDDEN);
    layer_kernel<<<LBLOCKS, 256, 0, stream>>>(x_out, x_a, offs, csr_col,
                                              W + 1 * HIDDEN * HIDDEN, b + 1 * HIDDEN);
    layer_kernel<<<LBLOCKS, 256, 0, stream>>>(x_a, x_out, offs, csr_col,
                                              W + 2 * HIDDEN * HIDDEN, b + 2 * HIDDEN);
}

// Round 4
// 327.785 us; speedup vs baseline: 1.6495x; 1.6495x over previous
//
#include <hip/hip_runtime.h>
#include <hip/hip_bf16.h>

#define N_NODES    100000
#define N_EDGES    1200000
#define HIDDEN     64
#define NUM_ATOM   100
#define SCAN_BLOCK 256

// ---------------------------------------------------------------------------
// rank[e] = deg[row[e]]++   (int atomics, L2-resident histogram; rank seq write)
__global__ void deg_rank_kernel(const int* __restrict__ row,
                                int* __restrict__ deg, int* __restrict__ rank) {
    int e = blockIdx.x * blockDim.x + threadIdx.x;
    if (e >= N_EDGES) return;
    rank[e] = atomicAdd(&deg[row[e]], 1);
}

// Block-level exclusive scan (Hillis-Steele) + per-block sums
__global__ void scan1_kernel(const int* __restrict__ deg, int* __restrict__ offs,
                             int* __restrict__ bsums) {
    __shared__ int tmp[SCAN_BLOCK];
    int i = blockIdx.x * SCAN_BLOCK + threadIdx.x;
    int v = (i < N_NODES) ? deg[i] : 0;
    tmp[threadIdx.x] = v;
    __syncthreads();
    for (int off = 1; off < SCAN_BLOCK; off <<= 1) {
        int t = (threadIdx.x >= off) ? tmp[threadIdx.x - off] : 0;
        __syncthreads();
        tmp[threadIdx.x] += t;
        __syncthreads();
    }
    if (i < N_NODES) offs[i] = tmp[threadIdx.x] - v;   // exclusive
    if (threadIdx.x == SCAN_BLOCK - 1) bsums[blockIdx.x] = tmp[threadIdx.x];
}

__global__ void scan2_kernel(int* __restrict__ bsums, int nb) {
    __shared__ int tmp[512];
    int v = (threadIdx.x < nb) ? bsums[threadIdx.x] : 0;
    tmp[threadIdx.x] = v;
    __syncthreads();
    for (int off = 1; off < 512; off <<= 1) {
        int t = (threadIdx.x >= off) ? tmp[threadIdx.x - off] : 0;
        __syncthreads();
        tmp[threadIdx.x] += t;
        __syncthreads();
    }
    if (threadIdx.x < nb) bsums[threadIdx.x] = tmp[threadIdx.x] - v;  // exclusive
}

__global__ void scan3_kernel(int* __restrict__ offs, const int* __restrict__ bsums) {
    int i = blockIdx.x * SCAN_BLOCK + threadIdx.x;
    if (i >= N_NODES) return;
    offs[i] += bsums[blockIdx.x];
}

// csr_col[offs[row[e]] + rank[e]] = col[e]   (no atomics)
__global__ void fill_kernel(const int* __restrict__ row, const int* __restrict__ col,
                            const int* __restrict__ offs, const int* __restrict__ rank,
                            int* __restrict__ csr_col) {
    int e = blockIdx.x * blockDim.x + threadIdx.x;
    if (e >= N_EDGES) return;
    csr_col[offs[row[e]] + rank[e]] = col[e];
}

// ---------------------------------------------------------------------------
// Layer 1 fused with embedding: emb (25.6 KB) in LDS; gather reads z[c] (4 B,
// L2-resident) per edge. Output bf16.
__global__ __launch_bounds__(256) void layer1_kernel(
        const int* __restrict__ z, const float* __restrict__ emb,
        __hip_bfloat16* __restrict__ xout,
        const int* __restrict__ offs, const int* __restrict__ csr_col,
        const float* __restrict__ W, const float* __restrict__ b) {
    __shared__ float Es[NUM_ATOM * 64];   // 25.6 KB
    __shared__ float Ws[64][65];          // staging for Wr; +1 pad
    __shared__ float xs[4][64];

    int t = threadIdx.x;
    for (int i = t; i < NUM_ATOM * 64; i += 256) Es[i] = emb[i];
    for (int i = t; i < 4096; i += 256) Ws[i >> 6][i & 63] = W[i];
    __syncthreads();

    int lane = t & 63, w = t >> 6;
    float Wr[64];
    #pragma unroll
    for (int k = 0; k < 64; ++k) Wr[k] = Ws[lane][k];
    float bb = b[lane];
    int tw = gridDim.x * 4;

    for (int n = blockIdx.x * 4 + w; n < N_NODES; n += tw) {
        int s = offs[n];
        int e = (n == N_NODES - 1) ? N_EDGES : offs[n + 1];

        float acc = Es[z[n] * 64 + lane];
        float a0=0.f,a1=0.f,a2=0.f,a3=0.f,a4=0.f,a5=0.f,a6=0.f,a7=0.f;
        int k = s;
        for (; k + 7 < e; k += 8) {
            int c0=csr_col[k],   c1=csr_col[k+1], c2=csr_col[k+2], c3=csr_col[k+3];
            int c4=csr_col[k+4], c5=csr_col[k+5], c6=csr_col[k+6], c7=csr_col[k+7];
            int z0=z[c0], z1=z[c1], z2=z[c2], z3=z[c3];
            int z4=z[c4], z5=z[c5], z6=z[c6], z7=z[c7];
            a0 += Es[z0*64+lane]; a1 += Es[z1*64+lane];
            a2 += Es[z2*64+lane]; a3 += Es[z3*64+lane];
            a4 += Es[z4*64+lane]; a5 += Es[z5*64+lane];
            a6 += Es[z6*64+lane]; a7 += Es[z7*64+lane];
        }
        for (; k < e; ++k) acc += Es[z[csr_col[k]] * 64 + lane];
        acc += ((a0+a1)+(a2+a3)) + ((a4+a5)+(a6+a7));

        xs[w][lane] = acc;   // wave-synchronous exchange

        float o = bb;
        #pragma unroll
        for (int k4 = 0; k4 < 16; ++k4) {
            float4 xv = *reinterpret_cast<const float4*>(&xs[w][k4 * 4]);
            o = fmaf(xv.x, Wr[k4*4+0], o);
            o = fmaf(xv.y, Wr[k4*4+1], o);
            o = fmaf(xv.z, Wr[k4*4+2], o);
            o = fmaf(xv.w, Wr[k4*4+3], o);
        }
        xout[n * 64 + lane] = __float2bfloat16(fmaxf(o, 0.0f));
    }
}

// ---------------------------------------------------------------------------
// Layers 2..3 (round-2 structure): bf16 gather + residual, f32 accumulate,
// W in VGPRs, 4 independent gather chains, ReLU. LAST writes f32 to d_out.
template<bool LAST>
__global__ __launch_bounds__(256) void layer_kernel(
        const __hip_bfloat16* __restrict__ xin,
        __hip_bfloat16* __restrict__ xout_b,
        float* __restrict__ xout_f,
        const int* __restrict__ offs, const int* __restrict__ csr_col,
        const float* __restrict__ W, const float* __restrict__ b) {
    __shared__ float Ws[64][65];
    __shared__ float xs[4][64];

    int t = threadIdx.x;
    for (int i = t; i < 4096; i += 256) Ws[i >> 6][i & 63] = W[i];
    __syncthreads();

    int lane = t & 63, w = t >> 6;
    float Wr[64];
    #pragma unroll
    for (int k = 0; k < 64; ++k) Wr[k] = Ws[lane][k];
    float bb = b[lane];
    int tw = gridDim.x * 4;

    for (int n = blockIdx.x * 4 + w; n < N_NODES; n += tw) {
        int s = offs[n];
        int e = (n == N_NODES - 1) ? N_EDGES : offs[n + 1];

        float acc = __bfloat162float(xin[n * 64 + lane]);
        float a0 = 0.f, a1 = 0.f, a2 = 0.f, a3 = 0.f;
        int k = s;
        for (; k + 3 < e; k += 4) {
            int c0 = csr_col[k],     c1 = csr_col[k + 1];
            int c2 = csr_col[k + 2], c3 = csr_col[k + 3];
            a0 += __bfloat162float(xin[c0 * 64 + lane]);
            a1 += __bfloat162float(xin[c1 * 64 + lane]);
            a2 += __bfloat162float(xin[c2 * 64 + lane]);
            a3 += __bfloat162float(xin[c3 * 64 + lane]);
        }
        for (; k < e; ++k) acc += __bfloat162float(xin[csr_col[k] * 64 + lane]);
        acc += (a0 + a1) + (a2 + a3);

        xs[w][lane] = acc;   // wave-synchronous exchange

        float o = bb;
        #pragma unroll
        for (int k4 = 0; k4 < 16; ++k4) {
            float4 xv = *reinterpret_cast<const float4*>(&xs[w][k4 * 4]);
            o = fmaf(xv.x, Wr[k4*4+0], o);
            o = fmaf(xv.y, Wr[k4*4+1], o);
            o = fmaf(xv.z, Wr[k4*4+2], o);
            o = fmaf(xv.w, Wr[k4*4+3], o);
        }
        o = fmaxf(o, 0.0f);
        if (LAST) xout_f[n * 64 + lane] = o;
        else      xout_b[n * 64 + lane] = __float2bfloat16(o);
    }
}

// ---------------------------------------------------------------------------
extern "C" void kernel_launch(void* const* d_in, const int* in_sizes, int n_in,
                              void* d_out, int out_size, void* d_ws, size_t ws_size,
                              hipStream_t stream) {
    const int*   z          = (const int*)d_in[0];
    const int*   edge_index = (const int*)d_in[1];
    const float* emb        = (const float*)d_in[2];
    const float* W          = (const float*)d_in[3];
    const float* b          = (const float*)d_in[4];

    const int* row = edge_index;             // edge_index[0]
    const int* col = edge_index + N_EDGES;   // edge_index[1]

    float* x_out = (float*)d_out;            // [N][64] f32 (final only)

    // workspace layout (rank aliases xb_a: rank is dead before layer1 writes)
    char* wsb = (char*)d_ws;
    __hip_bfloat16* xb_a = (__hip_bfloat16*)wsb;                // 12,800,000 B
    int*            rank = (int*)wsb;                           // 4,800,000 B alias
    __hip_bfloat16* xb_b = (__hip_bfloat16*)(wsb + 12800000);   // 12,800,000 B
    int*   csr_col = (int*)(wsb + 25600000);                    //  4,800,000 B
    int*   deg     = (int*)(wsb + 30400000);                    //    400,128 B
    int*   offs    = (int*)(wsb + 30800128);                    //    400,128 B
    int*   bsums   = (int*)(wsb + 31200256);                    //      2,048 B

    const int nb = (N_NODES + SCAN_BLOCK - 1) / SCAN_BLOCK;     // 391

    // ---- build CSR ----
    hipMemsetAsync(deg, 0, N_NODES * sizeof(int), stream);
    deg_rank_kernel<<<(N_EDGES + 255) / 256, 256, 0, stream>>>(row, deg, rank);
    scan1_kernel<<<nb, SCAN_BLOCK, 0, stream>>>(deg, offs, bsums);
    scan2_kernel<<<1, 512, 0, stream>>>(bsums, nb);
    scan3_kernel<<<nb, SCAN_BLOCK, 0, stream>>>(offs, bsums);
    fill_kernel<<<(N_EDGES + 255) / 256, 256, 0, stream>>>(row, col, offs, rank, csr_col);

    // ---- 3 fused layers: L1(emb)->xb_a, L2: xb_a->xb_b, L3: xb_b->d_out ----
    const int LBLOCKS = 1280;
    layer1_kernel<<<LBLOCKS, 256, 0, stream>>>(z, emb, xb_a, offs, csr_col,
                                               W + 0 * HIDDEN * HIDDEN, b + 0 * HIDDEN);
    layer_kernel<false><<<LBLOCKS, 256, 0, stream>>>(xb_a, xb_b, (float*)nullptr,
                                                     offs, csr_col,
                                                     W + 1 * HIDDEN * HIDDEN, b + 1 * HIDDEN);
    layer_kernel<true><<<LBLOCKS, 256, 0, stream>>>(xb_b, (__hip_bfloat16*)nullptr, x_out,
                                                    offs, csr_col,
                                                    W + 2 * HIDDEN * HIDDEN, b + 2 * HIDDEN);
}

// Round 5
// 313.901 us; speedup vs baseline: 1.7225x; 1.0442x over previous
//
#include <hip/hip_runtime.h>
#include <hip/hip_bf16.h>

#define N_NODES    100000
#define N_EDGES    1200000
#define HIDDEN     64
#define NUM_ATOM   100
#define SCAN_BLOCK 256

// ---------------------------------------------------------------------------
// rank[e] = deg[row[e]]++   (int atomics, L2-resident histogram; rank seq write)
__global__ void deg_rank_kernel(const int* __restrict__ row,
                                int* __restrict__ deg, int* __restrict__ rank) {
    int e = blockIdx.x * blockDim.x + threadIdx.x;
    if (e >= N_EDGES) return;
    rank[e] = atomicAdd(&deg[row[e]], 1);
}

// Block-level exclusive scan (Hillis-Steele) + per-block sums
__global__ void scan1_kernel(const int* __restrict__ deg, int* __restrict__ offs,
                             int* __restrict__ bsums) {
    __shared__ int tmp[SCAN_BLOCK];
    int i = blockIdx.x * SCAN_BLOCK + threadIdx.x;
    int v = (i < N_NODES) ? deg[i] : 0;
    tmp[threadIdx.x] = v;
    __syncthreads();
    for (int off = 1; off < SCAN_BLOCK; off <<= 1) {
        int t = (threadIdx.x >= off) ? tmp[threadIdx.x - off] : 0;
        __syncthreads();
        tmp[threadIdx.x] += t;
        __syncthreads();
    }
    if (i < N_NODES) offs[i] = tmp[threadIdx.x] - v;   // exclusive
    if (threadIdx.x == SCAN_BLOCK - 1) bsums[blockIdx.x] = tmp[threadIdx.x];
}

__global__ void scan2_kernel(int* __restrict__ bsums, int nb) {
    __shared__ int tmp[512];
    int v = (threadIdx.x < nb) ? bsums[threadIdx.x] : 0;
    tmp[threadIdx.x] = v;
    __syncthreads();
    for (int off = 1; off < 512; off <<= 1) {
        int t = (threadIdx.x >= off) ? tmp[threadIdx.x - off] : 0;
        __syncthreads();
        tmp[threadIdx.x] += t;
        __syncthreads();
    }
    if (threadIdx.x < nb) bsums[threadIdx.x] = tmp[threadIdx.x] - v;  // exclusive
}

__global__ void scan3_kernel(int* __restrict__ offs, const int* __restrict__ bsums) {
    int i = blockIdx.x * SCAN_BLOCK + threadIdx.x;
    if (i >= N_NODES) return;
    offs[i] += bsums[blockIdx.x];
}

// csr_col[offs[row[e]] + rank[e]] = col[e]   (no atomics)
__global__ void fill_kernel(const int* __restrict__ row, const int* __restrict__ col,
                            const int* __restrict__ offs, const int* __restrict__ rank,
                            int* __restrict__ csr_col) {
    int e = blockIdx.x * blockDim.x + threadIdx.x;
    if (e >= N_EDGES) return;
    csr_col[offs[row[e]] + rank[e]] = col[e];
}

// ---------------------------------------------------------------------------
// Layer 1 fused with embedding. LDS = bf16 emb table (12.8 KB) + xs only;
// W goes straight to VGPRs from global (L1/L2-resident 16 KB table).
__global__ __launch_bounds__(256) void layer1_kernel(
        const int* __restrict__ z, const float* __restrict__ emb,
        __hip_bfloat16* __restrict__ xout,
        const int* __restrict__ offs, const int* __restrict__ csr_col,
        const float* __restrict__ W, const float* __restrict__ b) {
    __shared__ __hip_bfloat16 Es[NUM_ATOM * 64];   // 12.8 KB
    __shared__ float xs[4][64];

    int t = threadIdx.x;
    for (int i = t; i < NUM_ATOM * 64; i += 256)
        Es[i] = __float2bfloat16(emb[i]);

    int lane = t & 63, w = t >> 6;
    float Wr[64];
    #pragma unroll
    for (int k4 = 0; k4 < 16; ++k4) {
        float4 wv = *reinterpret_cast<const float4*>(W + lane * 64 + k4 * 4);
        Wr[k4*4+0] = wv.x; Wr[k4*4+1] = wv.y;
        Wr[k4*4+2] = wv.z; Wr[k4*4+3] = wv.w;
    }
    float bb = b[lane];
    __syncthreads();

    int tw = gridDim.x * 4;
    for (int n = blockIdx.x * 4 + w; n < N_NODES; n += tw) {
        int s = offs[n];
        int e = (n == N_NODES - 1) ? N_EDGES : offs[n + 1];

        float acc = __bfloat162float(Es[z[n] * 64 + lane]);
        float a0=0.f,a1=0.f,a2=0.f,a3=0.f,a4=0.f,a5=0.f,a6=0.f,a7=0.f;
        int k = s;
        for (; k + 7 < e; k += 8) {
            int c0=csr_col[k],   c1=csr_col[k+1], c2=csr_col[k+2], c3=csr_col[k+3];
            int c4=csr_col[k+4], c5=csr_col[k+5], c6=csr_col[k+6], c7=csr_col[k+7];
            int z0=z[c0], z1=z[c1], z2=z[c2], z3=z[c3];
            int z4=z[c4], z5=z[c5], z6=z[c6], z7=z[c7];
            a0 += __bfloat162float(Es[z0*64+lane]);
            a1 += __bfloat162float(Es[z1*64+lane]);
            a2 += __bfloat162float(Es[z2*64+lane]);
            a3 += __bfloat162float(Es[z3*64+lane]);
            a4 += __bfloat162float(Es[z4*64+lane]);
            a5 += __bfloat162float(Es[z5*64+lane]);
            a6 += __bfloat162float(Es[z6*64+lane]);
            a7 += __bfloat162float(Es[z7*64+lane]);
        }
        for (; k < e; ++k) acc += __bfloat162float(Es[z[csr_col[k]] * 64 + lane]);
        acc += ((a0+a1)+(a2+a3)) + ((a4+a5)+(a6+a7));

        xs[w][lane] = acc;   // wave-synchronous exchange

        float o = bb;
        #pragma unroll
        for (int k4 = 0; k4 < 16; ++k4) {
            float4 xv = *reinterpret_cast<const float4*>(&xs[w][k4 * 4]);
            o = fmaf(xv.x, Wr[k4*4+0], o);
            o = fmaf(xv.y, Wr[k4*4+1], o);
            o = fmaf(xv.z, Wr[k4*4+2], o);
            o = fmaf(xv.w, Wr[k4*4+3], o);
        }
        xout[n * 64 + lane] = __float2bfloat16(fmaxf(o, 0.0f));
    }
}

// ---------------------------------------------------------------------------
// Layers 2..3: bf16 gather + residual, f32 accumulate, W in VGPRs,
// 4 independent gather chains, ReLU. LAST writes f32 to d_out.
template<bool LAST>
__global__ __launch_bounds__(256) void layer_kernel(
        const __hip_bfloat16* __restrict__ xin,
        __hip_bfloat16* __restrict__ xout_b,
        float* __restrict__ xout_f,
        const int* __restrict__ offs, const int* __restrict__ csr_col,
        const float* __restrict__ W, const float* __restrict__ b) {
    __shared__ float Ws[64][65];
    __shared__ float xs[4][64];

    int t = threadIdx.x;
    for (int i = t; i < 4096; i += 256) Ws[i >> 6][i & 63] = W[i];
    __syncthreads();

    int lane = t & 63, w = t >> 6;
    float Wr[64];
    #pragma unroll
    for (int k = 0; k < 64; ++k) Wr[k] = Ws[lane][k];
    float bb = b[lane];
    int tw = gridDim.x * 4;

    for (int n = blockIdx.x * 4 + w; n < N_NODES; n += tw) {
        int s = offs[n];
        int e = (n == N_NODES - 1) ? N_EDGES : offs[n + 1];

        float acc = __bfloat162float(xin[n * 64 + lane]);
        float a0 = 0.f, a1 = 0.f, a2 = 0.f, a3 = 0.f;
        int k = s;
        for (; k + 3 < e; k += 4) {
            int c0 = csr_col[k],     c1 = csr_col[k + 1];
            int c2 = csr_col[k + 2], c3 = csr_col[k + 3];
            a0 += __bfloat162float(xin[c0 * 64 + lane]);
            a1 += __bfloat162float(xin[c1 * 64 + lane]);
            a2 += __bfloat162float(xin[c2 * 64 + lane]);
            a3 += __bfloat162float(xin[c3 * 64 + lane]);
        }
        for (; k < e; ++k) acc += __bfloat162float(xin[csr_col[k] * 64 + lane]);
        acc += (a0 + a1) + (a2 + a3);

        xs[w][lane] = acc;   // wave-synchronous exchange

        float o = bb;
        #pragma unroll
        for (int k4 = 0; k4 < 16; ++k4) {
            float4 xv = *reinterpret_cast<const float4*>(&xs[w][k4 * 4]);
            o = fmaf(xv.x, Wr[k4*4+0], o);
            o = fmaf(xv.y, Wr[k4*4+1], o);
            o = fmaf(xv.z, Wr[k4*4+2], o);
            o = fmaf(xv.w, Wr[k4*4+3], o);
        }
        o = fmaxf(o, 0.0f);
        if (LAST) xout_f[n * 64 + lane] = o;
        else      xout_b[n * 64 + lane] = __float2bfloat16(o);
    }
}

// ---------------------------------------------------------------------------
extern "C" void kernel_launch(void* const* d_in, const int* in_sizes, int n_in,
                              void* d_out, int out_size, void* d_ws, size_t ws_size,
                              hipStream_t stream) {
    const int*   z          = (const int*)d_in[0];
    const int*   edge_index = (const int*)d_in[1];
    const float* emb        = (const float*)d_in[2];
    const float* W          = (const float*)d_in[3];
    const float* b          = (const float*)d_in[4];

    const int* row = edge_index;             // edge_index[0]
    const int* col = edge_index + N_EDGES;   // edge_index[1]

    float* x_out = (float*)d_out;            // [N][64] f32 (final only)

    // workspace layout (rank aliases xb_a: rank is dead before layer1 writes)
    char* wsb = (char*)d_ws;
    __hip_bfloat16* xb_a = (__hip_bfloat16*)wsb;                // 12,800,000 B
    int*            rank = (int*)wsb;                           // 4,800,000 B alias
    __hip_bfloat16* xb_b = (__hip_bfloat16*)(wsb + 12800000);   // 12,800,000 B
    int*   csr_col = (int*)(wsb + 25600000);                    //  4,800,000 B
    int*   deg     = (int*)(wsb + 30400000);                    //    400,128 B
    int*   offs    = (int*)(wsb + 30800128);                    //    400,128 B
    int*   bsums   = (int*)(wsb + 31200256);                    //      2,048 B

    const int nb = (N_NODES + SCAN_BLOCK - 1) / SCAN_BLOCK;     // 391

    // ---- build CSR ----
    hipMemsetAsync(deg, 0, N_NODES * sizeof(int), stream);
    deg_rank_kernel<<<(N_EDGES + 255) / 256, 256, 0, stream>>>(row, deg, rank);
    scan1_kernel<<<nb, SCAN_BLOCK, 0, stream>>>(deg, offs, bsums);
    scan2_kernel<<<1, 512, 0, stream>>>(bsums, nb);
    scan3_kernel<<<nb, SCAN_BLOCK, 0, stream>>>(offs, bsums);
    fill_kernel<<<(N_EDGES + 255) / 256, 256, 0, stream>>>(row, col, offs, rank, csr_col);

    // ---- 3 fused layers: L1(emb)->xb_a, L2: xb_a->xb_b, L3: xb_b->d_out ----
    layer1_kernel<<<2048, 256, 0, stream>>>(z, emb, xb_a, offs, csr_col,
                                            W + 0 * HIDDEN * HIDDEN, b + 0 * HIDDEN);
    layer_kernel<false><<<1280, 256, 0, stream>>>(xb_a, xb_b, (float*)nullptr,
                                                  offs, csr_col,
                                                  W + 1 * HIDDEN * HIDDEN, b + 1 * HIDDEN);
    layer_kernel<true><<<1280, 256, 0, stream>>>(xb_b, (__hip_bfloat16*)nullptr, x_out,
                                                 offs, csr_col,
                                                 W + 2 * HIDDEN * HIDDEN, b + 2 * HIDDEN);
}